// Round 2
// baseline (163.530 us; speedup 1.0000x reference)
//
#include <hip/hip_runtime.h>
#include <hip/hip_bf16.h>

#define H_DIM   64
#define T_STEPS 128
#define B_TOT   4096
#define BB      8     // rows per block; 512 blocks -> 2 blocks/CU -> 2 waves/SIMD
#define AK      200   // padded A-row stride in ushorts (192 + 8): 400B, 16B-aligned
#define NTHREADS 256

typedef __attribute__((ext_vector_type(8))) short short8;
typedef __attribute__((ext_vector_type(4))) float f32x4;

__device__ __forceinline__ ushort f2bf(float f) {
    unsigned u = __float_as_uint(f);
    u = (u + 0x7fffu + ((u >> 16) & 1u)) >> 16;   // RNE, finite inputs only
    return (ushort)u;
}
__device__ __forceinline__ float bf2f(ushort s) {
    return __uint_as_float(((unsigned)s) << 16);
}
__device__ __forceinline__ float fast_sigmoid(float x) {
    float e = __expf(-x);
    return __builtin_amdgcn_rcpf(1.0f + e);
}
__device__ __forceinline__ float fast_tanh(float x) {
    float ax = fminf(fabsf(x), 15.0f);            // clamp: c can be O(100), exp(2c) would overflow
    float e2 = __expf(2.0f * ax);
    float t = 1.0f - 2.0f * __builtin_amdgcn_rcpf(e2 + 1.0f);
    return copysignf(t, x);
}

// A = [x (64) | h_hi (64) | h_lo (64)] bf16, K=192, M-tile=16 with BB=8 valid rows.
// Weights live permanently in registers as MFMA B-fragments; W_hh fragments are
// reused for the h_lo correction term (compensated bf16 h).
__global__ __launch_bounds__(NTHREADS) void lstm_fused(
    const int* __restrict__ inst, const float* __restrict__ embed,
    const float* __restrict__ Wih, const float* __restrict__ Whh,
    const float* __restrict__ bih, const float* __restrict__ bhh,
    float* __restrict__ out)
{
    __shared__ __align__(16) ushort sA[2][16][AK];   // M-tile is 16 rows; rows BB..15 stay zero
    __shared__ int sInst[BB * T_STEPS];

    const int tid  = (int)threadIdx.x;
    const int w    = tid >> 6;     // wave 0..3 -> owns h-cols w*16..w*16+15
    const int l    = tid & 63;
    const int lrow = l & 15;       // A-row (m) for reads / n-col for B-frags & C/D
    const int lk   = l >> 4;       // k-block
    const int b0   = (int)blockIdx.x * BB;

    // stage this block's instruction indices (BB rows x 128 steps, contiguous)
    for (int i = tid; i < BB * T_STEPS; i += NTHREADS)
        sInst[i] = inst[b0 * T_STEPS + i];

    // zero the whole A staging area once (covers h0=0 and the unused M rows)
    for (int i = tid; i < 2 * 16 * AK; i += NTHREADS)
        ((ushort*)sA)[i] = 0;
    __syncthreads();

    // weight B-fragments: wf[gate][kf]; kf 0,1 -> W_ih k:0..63 ; kf 2,3 -> W_hh k:0..63
    // B[k][n] = W[n][k]; lane holds n = lrow (out col), k = kf*32 + lk*8 + j (contiguous)
    short8 wf[4][4];
    float bias[4];
#pragma unroll
    for (int gi = 0; gi < 4; ++gi) {
        const int col = gi * 64 + w * 16 + lrow;       // gate output column 0..255
        bias[gi] = bih[col] + bhh[col];
#pragma unroll
        for (int kf = 0; kf < 4; ++kf) {
            const float* src = (kf < 2 ? Wih : Whh) + (long)col * H_DIM + (kf & 1) * 32 + lk * 8;
            short8 v;
#pragma unroll
            for (int j = 0; j < 8; ++j) v[j] = (short)f2bf(src[j]);
            wf[gi][kf] = v;
        }
    }

    // embedding gather mapping: thread -> (row gr, 4-float column chunk gc)
    const int gr = tid >> 4;       // 0..15; only gr<BB active
    const int gc = tid & 15;
    if (gr < BB) {
        const int idx = sInst[gr * T_STEPS + 0];
        const float4 xv = *reinterpret_cast<const float4*>(embed + (long)idx * H_DIM + gc * 4);
        ushort4 xb = make_ushort4(f2bf(xv.x), f2bf(xv.y), f2bf(xv.z), f2bf(xv.w));
        *reinterpret_cast<ushort4*>(&sA[0][gr][gc * 4]) = xb;
    }
    __syncthreads();

    f32x4 creg = {0.f, 0.f, 0.f, 0.f};   // c in D-layout: row = lk*4+r, col = w*16+lrow
    f32x4 hreg = {0.f, 0.f, 0.f, 0.f};

    for (int t = 0; t < T_STEPS; ++t) {
        const int buf = t & 1;

        // prefetch next step's embedding row chunk (global -> reg), hidden under MFMA
        float4 xv = {0.f, 0.f, 0.f, 0.f};
        const bool pf = (t + 1 < T_STEPS);
        if (pf && gr < BB) {
            const int idx = sInst[gr * T_STEPS + t + 1];
            xv = *reinterpret_cast<const float4*>(embed + (long)idx * H_DIM + gc * 4);
        }

        // A-fragments: lane reads A[m=lrow][k = kf*32 + lk*8 + 0..7] (16B contiguous)
        short8 a[6];
#pragma unroll
        for (int kf = 0; kf < 6; ++kf)
            a[kf] = *reinterpret_cast<const short8*>(&sA[buf][lrow][kf * 32 + lk * 8]);

        // gates = A @ W^T + (b_ih + b_hh); acc seeded with bias (same for all rows)
        f32x4 acc[4];
#pragma unroll
        for (int gi = 0; gi < 4; ++gi) {
            f32x4 accv = {bias[gi], bias[gi], bias[gi], bias[gi]};
            accv = __builtin_amdgcn_mfma_f32_16x16x32_bf16(a[0], wf[gi][0], accv, 0, 0, 0);
            accv = __builtin_amdgcn_mfma_f32_16x16x32_bf16(a[1], wf[gi][1], accv, 0, 0, 0);
            accv = __builtin_amdgcn_mfma_f32_16x16x32_bf16(a[2], wf[gi][2], accv, 0, 0, 0);
            accv = __builtin_amdgcn_mfma_f32_16x16x32_bf16(a[3], wf[gi][3], accv, 0, 0, 0);
            accv = __builtin_amdgcn_mfma_f32_16x16x32_bf16(a[4], wf[gi][2], accv, 0, 0, 0);  // h_lo
            accv = __builtin_amdgcn_mfma_f32_16x16x32_bf16(a[5], wf[gi][3], accv, 0, 0, 0);  // h_lo
            acc[gi] = accv;
        }

        // cell update, f32, in-register (gate order i,f,g,o)
#pragma unroll
        for (int r = 0; r < 4; ++r) {
            const float iv = fast_sigmoid(acc[0][r]);
            const float fv = fast_sigmoid(acc[1][r]);
            const float gv = fast_tanh(acc[2][r]);
            const float ov = fast_sigmoid(acc[3][r]);
            const float cn = fv * creg[r] + iv * gv;
            creg[r] = cn;
            hreg[r] = ov * fast_tanh(cn);
        }

        // publish h (hi+lo bf16) and prefetched x into the other buffer
        if (pf) {
            const int ob = buf ^ 1;
            if (lk < BB / 4) {     // only rows < BB are real
                const int hcol = 64 + w * 16 + lrow;
#pragma unroll
                for (int r = 0; r < 4; ++r) {
                    const int row = lk * 4 + r;
                    const ushort hh = f2bf(hreg[r]);
                    const ushort hl = f2bf(hreg[r] - bf2f(hh));
                    sA[ob][row][hcol]      = hh;
                    sA[ob][row][hcol + 64] = hl;
                }
            }
            if (gr < BB) {
                ushort4 xb = make_ushort4(f2bf(xv.x), f2bf(xv.y), f2bf(xv.z), f2bf(xv.w));
                *reinterpret_cast<ushort4*>(&sA[ob][gr][gc * 4]) = xb;
            }
        }
        __syncthreads();
    }

    // final h (f32) -> out[B][H]
    if (lk < BB / 4) {
        const int ocol = w * 16 + lrow;
#pragma unroll
        for (int r = 0; r < 4; ++r) {
            const int row = lk * 4 + r;
            out[(long)(b0 + row) * H_DIM + ocol] = hreg[r];
        }
    }
}

extern "C" void kernel_launch(void* const* d_in, const int* in_sizes, int n_in,
                              void* d_out, int out_size, void* d_ws, size_t ws_size,
                              hipStream_t stream) {
    const int*   inst  = (const int*)  d_in[0];
    const float* embed = (const float*)d_in[1];
    const float* Wih   = (const float*)d_in[2];
    const float* Whh   = (const float*)d_in[3];
    const float* bih   = (const float*)d_in[4];
    const float* bhh   = (const float*)d_in[5];
    float* out = (float*)d_out;

    lstm_fused<<<B_TOT / BB, NTHREADS, 0, stream>>>(inst, embed, Wih, Whh, bih, bhh, out);
}

// Round 3
// 154.384 us; speedup vs baseline: 1.0592x; 1.0592x over previous
//
#include <hip/hip_runtime.h>
#include <hip/hip_bf16.h>

#define H_DIM   64
#define T_STEPS 128
#define B_TOT   4096
#define BB      16    // rows per block (full M tile, no waste)
#define AK      200   // padded A-row stride in ushorts (192 + 8): 400B, 16B-aligned
#define NTHREADS 512  // 8 waves: gh = w>>2 (gate pair), wg = w&3 (col group)

typedef __attribute__((ext_vector_type(8))) short short8;
typedef __attribute__((ext_vector_type(4))) float f32x4;

__device__ __forceinline__ ushort f2bf(float f) {
    unsigned u = __float_as_uint(f);
    u = (u + 0x7fffu + ((u >> 16) & 1u)) >> 16;   // RNE, finite inputs only
    return (ushort)u;
}
__device__ __forceinline__ float bf2f(ushort s) {
    return __uint_as_float(((unsigned)s) << 16);
}
__device__ __forceinline__ float fast_sigmoid(float x) {
    float e = __expf(-x);
    return __builtin_amdgcn_rcpf(1.0f + e);
}
__device__ __forceinline__ float fast_tanh(float x) {
    float ax = fminf(fabsf(x), 15.0f);            // clamp: c can be O(100), exp(2c) would overflow
    float e2 = __expf(2.0f * ax);
    float t = 1.0f - 2.0f * __builtin_amdgcn_rcpf(e2 + 1.0f);
    return copysignf(t, x);
}

// A = [x (64) | h_hi (64) | h_lo (64)] bf16, K=192, M=16 rows.
// 8 waves: waves gh=0 compute gates {i,f}, gh=1 compute {g,o}, each for 16 h-cols.
// Pre-activation gate values are exchanged via LDS (disjoint row sets -> one buffer);
// cell update is row-split: gh=0 owns r%4 in {0,1}, gh=1 owns r%4 in {2,3}.
__global__ __launch_bounds__(NTHREADS) void lstm_fused(
    const int* __restrict__ inst, const float* __restrict__ embed,
    const float* __restrict__ Wih, const float* __restrict__ Whh,
    const float* __restrict__ bih, const float* __restrict__ bhh,
    float* __restrict__ out)
{
    __shared__ __align__(16) ushort sA[2][BB][AK];   // 12.8 KB
    __shared__ int sInst[BB * T_STEPS];              // 8 KB
    __shared__ float2 sEx[BB][H_DIM];                // 8 KB gate exchange (pre-activation)

    const int tid  = (int)threadIdx.x;
    const int w    = tid >> 6;
    const int wg   = w & 3;        // col group: h-cols wg*16 .. wg*16+15
    const int gh   = w >> 2;       // 0 -> gates i,f ; 1 -> gates g,o
    const int l    = tid & 63;
    const int lrow = l & 15;       // A-row (m) for reads / n-col for B-frags & C/D
    const int lk   = l >> 4;       // k-block
    const int col  = wg * 16 + lrow;   // h-column this thread owns
    const int b0   = (int)blockIdx.x * BB;

    // stage this block's instruction indices (16 rows x 128 steps, contiguous)
    for (int i = tid; i < BB * T_STEPS; i += NTHREADS)
        sInst[i] = inst[b0 * T_STEPS + i];

    // zero A staging (h0 = 0; pad region)
    for (int i = tid; i < 2 * BB * AK; i += NTHREADS)
        ((ushort*)sA)[i] = 0;
    __syncthreads();

    // weight B-fragments for this wave's 2 gates: wf[gi][kf]
    // kf 0,1 -> W_ih k:0..63 ; kf 2,3 -> W_hh k:0..63 (reused for h_lo)
    short8 wf[2][4];
    float bias[2];
#pragma unroll
    for (int gi = 0; gi < 2; ++gi) {
        const int gcol = (gh * 2 + gi) * 64 + col;     // gate output column 0..255
        bias[gi] = bih[gcol] + bhh[gcol];
#pragma unroll
        for (int kf = 0; kf < 4; ++kf) {
            const float* src = (kf < 2 ? Wih : Whh) + (long)gcol * H_DIM + (kf & 1) * 32 + lk * 8;
            short8 v;
#pragma unroll
            for (int j = 0; j < 8; ++j) v[j] = (short)f2bf(src[j]);
            wf[gi][kf] = v;
        }
    }

    // embedding gather mapping: thread -> (row gr, float2 column chunk gc)
    const int gr = tid >> 5;       // 0..15
    const int gc = tid & 31;       // 0..31 float2 chunks of 64 floats
    {
        const int idx = sInst[gr * T_STEPS + 0];
        const float2 xv = *reinterpret_cast<const float2*>(embed + (long)idx * H_DIM + gc * 2);
        ushort2 xb = make_ushort2(f2bf(xv.x), f2bf(xv.y));
        *reinterpret_cast<ushort2*>(&sA[0][gr][gc * 2]) = xb;
    }
    __syncthreads();

    // c,h for the 2 rows this thread updates: row = lk*4 + gh*2 + j
    float creg[2] = {0.f, 0.f};
    float hreg[2] = {0.f, 0.f};

    for (int t = 0; t < T_STEPS; ++t) {
        const int buf = t & 1;
        const int ob  = buf ^ 1;
        const bool pf = (t + 1 < T_STEPS);

        // prefetch next step's embedding chunk (global -> reg), hidden under MFMA
        float2 xv = {0.f, 0.f};
        if (pf) {
            const int idx = sInst[gr * T_STEPS + t + 1];
            xv = *reinterpret_cast<const float2*>(embed + (long)idx * H_DIM + gc * 2);
        }

        // A-fragments: lane reads A[m=lrow][k = kf*32 + lk*8 + 0..7] (16B contiguous)
        short8 a[6];
#pragma unroll
        for (int kf = 0; kf < 6; ++kf)
            a[kf] = *reinterpret_cast<const short8*>(&sA[buf][lrow][kf * 32 + lk * 8]);

        // this wave's 2 gates = A @ W^T + bias (acc seeded with bias)
        f32x4 acc[2];
#pragma unroll
        for (int gi = 0; gi < 2; ++gi) {
            f32x4 accv = {bias[gi], bias[gi], bias[gi], bias[gi]};
            accv = __builtin_amdgcn_mfma_f32_16x16x32_bf16(a[0], wf[gi][0], accv, 0, 0, 0);
            accv = __builtin_amdgcn_mfma_f32_16x16x32_bf16(a[1], wf[gi][1], accv, 0, 0, 0);
            accv = __builtin_amdgcn_mfma_f32_16x16x32_bf16(a[2], wf[gi][2], accv, 0, 0, 0);
            accv = __builtin_amdgcn_mfma_f32_16x16x32_bf16(a[3], wf[gi][3], accv, 0, 0, 0);
            accv = __builtin_amdgcn_mfma_f32_16x16x32_bf16(a[4], wf[gi][2], accv, 0, 0, 0);  // h_lo
            accv = __builtin_amdgcn_mfma_f32_16x16x32_bf16(a[5], wf[gi][3], accv, 0, 0, 0);  // h_lo
            acc[gi] = accv;
        }

        // exchange: write raw gate pair for the 2 REMOTE rows (disjoint row sets)
#pragma unroll
        for (int j = 0; j < 2; ++j) {
            const int rr = (gh ? 0 : 2) + j;           // remote r
            sEx[lk * 4 + rr][col] = make_float2(acc[0][rr], acc[1][rr]);
        }

        // publish prefetched x into next buffer (independent of exchange)
        if (pf) {
            ushort2 xb = make_ushort2(f2bf(xv.x), f2bf(xv.y));
            *reinterpret_cast<ushort2*>(&sA[ob][gr][gc * 2]) = xb;
        }
        __syncthreads();   // exchange visible

        // cell update for this thread's 2 LOCAL rows (gate order i,f,g,o)
#pragma unroll
        for (int j = 0; j < 2; ++j) {
            const int r = gh * 2 + j;
            const float2 ex = sEx[lk * 4 + r][col];
            float vi, vf, vg, vo;
            if (gh == 0) { vi = acc[0][r]; vf = acc[1][r]; vg = ex.x; vo = ex.y; }
            else         { vg = acc[0][r]; vo = acc[1][r]; vi = ex.x; vf = ex.y; }
            const float iv = fast_sigmoid(vi);
            const float fv = fast_sigmoid(vf);
            const float gv = fast_tanh(vg);
            const float ov = fast_sigmoid(vo);
            const float cn = fv * creg[j] + iv * gv;
            creg[j] = cn;
            hreg[j] = ov * fast_tanh(cn);

            // publish h (hi + lo bf16) for next step
            if (pf) {
                const int row  = lk * 4 + r;
                const int hcol = 64 + col;
                const ushort hh = f2bf(hreg[j]);
                const ushort hl = f2bf(hreg[j] - bf2f(hh));
                sA[ob][row][hcol]      = hh;
                sA[ob][row][hcol + 64] = hl;
            }
        }
        __syncthreads();   // h published before next step's reads
    }

    // final h (f32) -> out[B][H]; each thread owns 2 (row,col) elements
#pragma unroll
    for (int j = 0; j < 2; ++j) {
        const int row = lk * 4 + gh * 2 + j;
        out[(long)(b0 + row) * H_DIM + col] = hreg[j];
    }
}

extern "C" void kernel_launch(void* const* d_in, const int* in_sizes, int n_in,
                              void* d_out, int out_size, void* d_ws, size_t ws_size,
                              hipStream_t stream) {
    const int*   inst  = (const int*)  d_in[0];
    const float* embed = (const float*)d_in[1];
    const float* Wih   = (const float*)d_in[2];
    const float* Whh   = (const float*)d_in[3];
    const float* bih   = (const float*)d_in[4];
    const float* bhh   = (const float*)d_in[5];
    float* out = (float*)d_out;

    lstm_fused<<<B_TOT / BB, NTHREADS, 0, stream>>>(inst, embed, Wih, Whh, bih, bhh, out);
}

// Round 4
// 113.495 us; speedup vs baseline: 1.4409x; 1.3603x over previous
//
#include <hip/hip_runtime.h>
#include <hip/hip_bf16.h>

#define H_DIM   64
#define T_STEPS 128
#define B_TOT   4096
#define BB      16    // rows per block (full M tile)
#define AK      200   // padded A-row stride in ushorts (192 + 8): 400B, 16B-aligned
#define NTHREADS 512  // 8 waves; wave w owns h-cols w*8..w*8+7, ALL 4 gates (2 gates packed per N-tile)

typedef __attribute__((ext_vector_type(8))) short short8;
typedef __attribute__((ext_vector_type(4))) float f32x4;

__device__ __forceinline__ ushort f2bf(float f) {
    unsigned u = __float_as_uint(f);
    u = (u + 0x7fffu + ((u >> 16) & 1u)) >> 16;   // RNE, finite inputs only
    return (ushort)u;
}
__device__ __forceinline__ float bf2f(ushort s) {
    return __uint_as_float(((unsigned)s) << 16);
}
__device__ __forceinline__ float fast_sigmoid(float x) {
    float e = __expf(-x);
    return __builtin_amdgcn_rcpf(1.0f + e);
}
__device__ __forceinline__ float fast_tanh(float x) {
    float ax = fminf(fabsf(x), 15.0f);            // clamp: c can be O(100), exp(2c) would overflow
    float e2 = __expf(2.0f * ax);
    float t = 1.0f - 2.0f * __builtin_amdgcn_rcpf(e2 + 1.0f);
    return copysignf(t, x);
}

// A = [x (64) | h_hi (64) | h_lo (64)] bf16, K=192, M=16 rows.
// B-fragments pack TWO gates' 8-col slices per 16-wide N-tile:
//   tile0 = [ i cols w*8..+7 (n=0..7) | f cols w*8..+7 (n=8..15) ]
//   tile1 = [ g ... | o ... ]
// so each wave computes all 4 gates for its 8 h-cols with 12 MFMAs, and the
// i<->f / g<->o exchange is an intra-wave shfl_xor(8) — no extra barrier.
__global__ __launch_bounds__(NTHREADS) void lstm_fused(
    const int* __restrict__ inst, const float* __restrict__ embed,
    const float* __restrict__ Wih, const float* __restrict__ Whh,
    const float* __restrict__ bih, const float* __restrict__ bhh,
    float* __restrict__ out)
{
    __shared__ __align__(16) ushort sA[2][BB][AK];   // 12.8 KB
    __shared__ int sInst[BB * T_STEPS];              // 8 KB

    const int tid  = (int)threadIdx.x;
    const int w    = tid >> 6;          // wave 0..7
    const int l    = tid & 63;
    const int lrow = l & 15;            // A-row (m) for reads / packed-n for B & C/D
    const int lk   = l >> 4;            // k-block; C/D rows are lk*4 + 0..3
    const bool losd = (lrow < 8);       // low side of the packed tile
    const int c    = w * 8 + (lrow & 7);   // h-column this thread updates
    const int b0   = (int)blockIdx.x * BB;

    // stage this block's instruction indices (16 rows x 128 steps, contiguous)
    for (int i = tid; i < BB * T_STEPS; i += NTHREADS)
        sInst[i] = inst[b0 * T_STEPS + i];

    // zero A staging (h0 = 0; pad region)
    for (int i = tid; i < 2 * BB * AK; i += NTHREADS)
        ((ushort*)sA)[i] = 0;
    __syncthreads();

    // weight B-fragments: tile q, lane holds gate = q*2 + (lrow>>3), col-in-gate = c
    // kf 0,1 -> W_ih k:0..63 ; kf 2,3 -> W_hh k:0..63 (reused for h_lo)
    short8 wf[2][4];
    float bias[2];
#pragma unroll
    for (int q = 0; q < 2; ++q) {
        const int gate = q * 2 + (lrow >> 3);
        const int gcol = gate * 64 + c;              // W output row 0..255
        bias[q] = bih[gcol] + bhh[gcol];
#pragma unroll
        for (int kf = 0; kf < 4; ++kf) {
            const float* src = (kf < 2 ? Wih : Whh) + (long)gcol * H_DIM + (kf & 1) * 32 + lk * 8;
            short8 v;
#pragma unroll
            for (int j = 0; j < 8; ++j) v[j] = (short)f2bf(src[j]);
            wf[q][kf] = v;
        }
    }

    // embedding gather mapping: 512 threads = 16 rows x 32 float2 chunks, exact
    const int gr = tid >> 5;       // 0..15
    const int gc = tid & 31;       // 0..31
    {
        const int idx = sInst[gr * T_STEPS + 0];
        const float2 xv = *reinterpret_cast<const float2*>(embed + (long)idx * H_DIM + gc * 2);
        ushort2 xb = make_ushort2(f2bf(xv.x), f2bf(xv.y));
        *reinterpret_cast<ushort2*>(&sA[0][gr][gc * 2]) = xb;
    }
    __syncthreads();

    // this thread updates rows lk*4 + (losd?0:2) + j, j=0..1, column c
    float creg[2] = {0.f, 0.f};
    float hreg[2] = {0.f, 0.f};

    for (int t = 0; t < T_STEPS; ++t) {
        const int buf = t & 1;
        const int ob  = buf ^ 1;
        const bool pf = (t + 1 < T_STEPS);

        // prefetch next step's embedding chunk (global -> reg), hidden under MFMA
        float2 xv = {0.f, 0.f};
        if (pf) {
            const int idx = sInst[gr * T_STEPS + t + 1];
            xv = *reinterpret_cast<const float2*>(embed + (long)idx * H_DIM + gc * 2);
        }

        // A-fragments: lane reads A[m=lrow][k = kf*32 + lk*8 + 0..7] (16B contiguous)
        short8 a[6];
#pragma unroll
        for (int kf = 0; kf < 6; ++kf)
            a[kf] = *reinterpret_cast<const short8*>(&sA[buf][lrow][kf * 32 + lk * 8]);

        // 2 packed gate tiles; each split into two 3-deep MFMA chains for ILP
        f32x4 acc[2];
#pragma unroll
        for (int q = 0; q < 2; ++q) {
            f32x4 pA = {bias[q], bias[q], bias[q], bias[q]};
            f32x4 pB = {0.f, 0.f, 0.f, 0.f};
            pA = __builtin_amdgcn_mfma_f32_16x16x32_bf16(a[0], wf[q][0], pA, 0, 0, 0);
            pB = __builtin_amdgcn_mfma_f32_16x16x32_bf16(a[1], wf[q][1], pB, 0, 0, 0);
            pA = __builtin_amdgcn_mfma_f32_16x16x32_bf16(a[2], wf[q][2], pA, 0, 0, 0);
            pB = __builtin_amdgcn_mfma_f32_16x16x32_bf16(a[3], wf[q][3], pB, 0, 0, 0);
            pA = __builtin_amdgcn_mfma_f32_16x16x32_bf16(a[4], wf[q][2], pA, 0, 0, 0);  // h_lo
            pB = __builtin_amdgcn_mfma_f32_16x16x32_bf16(a[5], wf[q][3], pB, 0, 0, 0);  // h_lo
            acc[q] = pA + pB;
        }

        // intra-wave gate exchange across the packed halves (lane ^ 8):
        // low lanes need partner's acc0/acc1 rows {0,1} worth of f,o;
        // high lanes need partner's rows {2,3} worth of i,g — send accordingly.
        const float e0 = __shfl_xor(losd ? acc[0][2] : acc[0][0], 8);  // vf(r0) / vi(r2)
        const float e1 = __shfl_xor(losd ? acc[0][3] : acc[0][1], 8);  // vf(r1) / vi(r3)
        const float e2 = __shfl_xor(losd ? acc[1][2] : acc[1][0], 8);  // vo(r0) / vg(r2)
        const float e3 = __shfl_xor(losd ? acc[1][3] : acc[1][1], 8);  // vo(r1) / vg(r3)

        // cell update for this thread's 2 rows (gate order i,f,g,o)
#pragma unroll
        for (int j = 0; j < 2; ++j) {
            const int r  = (losd ? 0 : 2) + j;
            const float ea = j ? e1 : e0;
            const float eb = j ? e3 : e2;
            const float vi = losd ? acc[0][r] : ea;
            const float vf = losd ? ea        : acc[0][r];
            const float vg = losd ? acc[1][r] : eb;
            const float vo = losd ? eb        : acc[1][r];
            const float iv = fast_sigmoid(vi);
            const float fv = fast_sigmoid(vf);
            const float gv = fast_tanh(vg);
            const float ov = fast_sigmoid(vo);
            const float cn = fv * creg[j] + iv * gv;
            creg[j] = cn;
            hreg[j] = ov * fast_tanh(cn);

            // publish h (hi + lo bf16) for next step
            if (pf) {
                const int row = lk * 4 + r;
                const ushort hh = f2bf(hreg[j]);
                const ushort hl = f2bf(hreg[j] - bf2f(hh));
                sA[ob][row][64 + c]  = hh;
                sA[ob][row][128 + c] = hl;
            }
        }

        // publish prefetched x into next buffer
        if (pf) {
            ushort2 xb = make_ushort2(f2bf(xv.x), f2bf(xv.y));
            *reinterpret_cast<ushort2*>(&sA[ob][gr][gc * 2]) = xb;
        }
        __syncthreads();   // everything in sA[ob] visible before next step
    }

    // final h (f32) -> out[B][H]; each thread owns 2 (row, col=c) elements
#pragma unroll
    for (int j = 0; j < 2; ++j) {
        const int row = lk * 4 + (losd ? 0 : 2) + j;
        out[(long)(b0 + row) * H_DIM + c] = hreg[j];
    }
}

extern "C" void kernel_launch(void* const* d_in, const int* in_sizes, int n_in,
                              void* d_out, int out_size, void* d_ws, size_t ws_size,
                              hipStream_t stream) {
    const int*   inst  = (const int*)  d_in[0];
    const float* embed = (const float*)d_in[1];
    const float* Wih   = (const float*)d_in[2];
    const float* Whh   = (const float*)d_in[3];
    const float* bih   = (const float*)d_in[4];
    const float* bhh   = (const float*)d_in[5];
    float* out = (float*)d_out;

    lstm_fused<<<B_TOT / BB, NTHREADS, 0, stream>>>(inst, embed, Wih, Whh, bih, bhh, out);
}

// Round 6
// 90.871 us; speedup vs baseline: 1.7996x; 1.2490x over previous
//
#include <hip/hip_runtime.h>
#include <hip/hip_bf16.h>

#define H_DIM   64
#define T_STEPS 128
#define B_TOT   4096
#define BB      16    // rows per block (full M tile)
#define SK      72    // padded row stride in halves for sX/sH (even bank classes)
#define NTHREADS 512  // 8 waves; wave w owns h-cols w*8..w*8+7, all 4 gates (2 gates per N-tile)

typedef _Float16 half8  __attribute__((ext_vector_type(8)));
typedef __fp16   fp16x2 __attribute__((ext_vector_type(2)));
typedef __attribute__((ext_vector_type(4))) float f32x4;

__device__ __forceinline__ float fast_sigmoid(float x) {
    // 1/(1+e^-x); x->-inf: exp->inf, rcp(inf)=0 -> 0; x->+inf: 1. No clamp needed.
    float e = __expf(-x);
    return __builtin_amdgcn_rcpf(1.0f + e);
}
__device__ __forceinline__ float fast_tanh(float x) {
    // 1 - 2/(e^{2x}+1); exact at both infinities (inf -> +1, 0 -> -1). No clamp.
    float e2 = __expf(2.0f * x);
    return 1.0f - 2.0f * __builtin_amdgcn_rcpf(e2 + 1.0f);
}

// A = [x (64) | h (64)] f16, K=128, M=16 rows. Weights in registers as f16 B-frags.
// B-fragments pack TWO gates' 8-col slices per 16-wide N-tile:
//   tile0 = [ i cols w*8..+7 | f cols w*8..+7 ],  tile1 = [ g | o ]
// i<->f / g<->o exchange via intra-wave shfl_xor(8); one barrier per step.
__global__ __launch_bounds__(NTHREADS) void lstm_fused(
    const int* __restrict__ inst, const float* __restrict__ embed,
    const float* __restrict__ Wih, const float* __restrict__ Whh,
    const float* __restrict__ bih, const float* __restrict__ bhh,
    float* __restrict__ out)
{
    __shared__ __align__(16) _Float16 sX[2][BB][SK];   // 4.6 KB  x staging (f16)
    __shared__ __align__(16) _Float16 sH[2][BB][SK];   // 4.6 KB  h staging (f16)
    __shared__ int sInst[BB * T_STEPS];                // 8 KB

    const int tid  = (int)threadIdx.x;
    const int w    = tid >> 6;          // wave 0..7
    const int l    = tid & 63;
    const int lrow = l & 15;            // A-row (m) / packed-n for B & C/D
    const int lk   = l >> 4;            // k-block; C/D rows are lk*4 + 0..3
    const bool losd = (lrow < 8);       // low side of the packed tile
    const int c    = w * 8 + (lrow & 7);   // h-column this thread updates
    const int b0   = (int)blockIdx.x * BB;

    // stage this block's instruction indices (16 rows x 128 steps, contiguous)
    for (int i = tid; i < BB * T_STEPS; i += NTHREADS)
        sInst[i] = inst[b0 * T_STEPS + i];

    // zero h buffer 0 (h0 = 0); sH[1] is fully overwritten each step
    for (int i = tid; i < BB * SK; i += NTHREADS)
        ((_Float16*)sH)[i] = (_Float16)0.0f;
    __syncthreads();

    // weight B-fragments (f16): tile q, lane holds gate = q*2 + (lrow>>3), col-in-gate = c
    // kf 0,1 -> W_ih k 0..63 ; kf 2,3 -> W_hh k 0..63
    half8 wf[2][4];
    float bias[2];
#pragma unroll
    for (int q = 0; q < 2; ++q) {
        const int gate = q * 2 + (lrow >> 3);
        const int gcol = gate * 64 + c;              // W output row 0..255
        bias[q] = bih[gcol] + bhh[gcol];
#pragma unroll
        for (int kf = 0; kf < 4; ++kf) {
            const float* src = (kf < 2 ? Wih : Whh) + (long)gcol * H_DIM + (kf & 1) * 32 + lk * 8;
            half8 v;
#pragma unroll
            for (int j = 0; j < 8; ++j) v[j] = (_Float16)src[j];  // RNE
            wf[q][kf] = v;
        }
    }

    // x staging mapping: 512 threads = 16 rows x 32 float2 chunks, exact cover
    const int xr = tid >> 5;       // 0..15
    const int xc = tid & 31;       // 0..31
    {
        const int idx = sInst[xr * T_STEPS + 0];
        const float2 xv = *reinterpret_cast<const float2*>(embed + (long)idx * H_DIM + xc * 2);
        fp16x2 hp = __builtin_amdgcn_cvt_pkrtz(xv.x, xv.y);
        *reinterpret_cast<fp16x2*>(&sX[0][xr][xc * 2]) = hp;
    }
    __syncthreads();

    // this thread updates rows lk*4 + (losd?0:2) + j, j=0..1, column c
    float creg[2] = {0.f, 0.f};
    float hreg[2] = {0.f, 0.f};

    for (int t = 0; t < T_STEPS; ++t) {
        const int buf = t & 1;
        const int ob  = buf ^ 1;
        const bool pf = (t + 1 < T_STEPS);

        // prefetch next step's x chunk (global -> reg), hidden under MFMA
        float2 xv = {0.f, 0.f};
        if (pf) {
            const int idx = sInst[xr * T_STEPS + t + 1];
            xv = *reinterpret_cast<const float2*>(embed + (long)idx * H_DIM + xc * 2);
        }

        // A-fragments (f16): x from sX, h from sH; lane (lrow,lk) reads 16B contiguous
        half8 a0 = *reinterpret_cast<const half8*>(&sX[buf][lrow][lk * 8]);
        half8 a1 = *reinterpret_cast<const half8*>(&sX[buf][lrow][32 + lk * 8]);
        half8 a2 = *reinterpret_cast<const half8*>(&sH[buf][lrow][lk * 8]);
        half8 a3 = *reinterpret_cast<const half8*>(&sH[buf][lrow][32 + lk * 8]);

        // 2 packed gate tiles; each split into two 2-deep MFMA chains for ILP
        f32x4 acc[2];
#pragma unroll
        for (int q = 0; q < 2; ++q) {
            f32x4 pA = {bias[q], bias[q], bias[q], bias[q]};
            f32x4 pB = {0.f, 0.f, 0.f, 0.f};
            pA = __builtin_amdgcn_mfma_f32_16x16x32_f16(a0, wf[q][0], pA, 0, 0, 0);
            pB = __builtin_amdgcn_mfma_f32_16x16x32_f16(a1, wf[q][1], pB, 0, 0, 0);
            pA = __builtin_amdgcn_mfma_f32_16x16x32_f16(a2, wf[q][2], pA, 0, 0, 0);
            pB = __builtin_amdgcn_mfma_f32_16x16x32_f16(a3, wf[q][3], pB, 0, 0, 0);
            acc[q] = pA + pB;
        }

        // intra-wave gate exchange across the packed halves (lane ^ 8)
        const float e0 = __shfl_xor(losd ? acc[0][2] : acc[0][0], 8);  // vf(r0) / vi(r2)
        const float e1 = __shfl_xor(losd ? acc[0][3] : acc[0][1], 8);  // vf(r1) / vi(r3)
        const float e2 = __shfl_xor(losd ? acc[1][2] : acc[1][0], 8);  // vo(r0) / vg(r2)
        const float e3 = __shfl_xor(losd ? acc[1][3] : acc[1][1], 8);  // vo(r1) / vg(r3)

        // cell update for this thread's 2 rows (gate order i,f,g,o)
#pragma unroll
        for (int j = 0; j < 2; ++j) {
            const int r  = (losd ? 0 : 2) + j;
            const float ea = j ? e1 : e0;
            const float eb = j ? e3 : e2;
            const float vi = losd ? acc[0][r] : ea;
            const float vf = losd ? ea        : acc[0][r];
            const float vg = losd ? acc[1][r] : eb;
            const float vo = losd ? eb        : acc[1][r];
            const float iv = fast_sigmoid(vi);
            const float fv = fast_sigmoid(vf);
            const float gv = fast_tanh(vg);
            const float ov = fast_sigmoid(vo);
            const float cn = fv * creg[j] + iv * gv;
            creg[j] = cn;
            hreg[j] = ov * fast_tanh(cn);

            // publish h (f16, RNE) for next step
            if (pf) {
                const int row = lk * 4 + r;
                sH[ob][row][c] = (_Float16)hreg[j];
            }
        }

        // publish prefetched x (f16, pkrtz) into next buffer
        if (pf) {
            fp16x2 hp = __builtin_amdgcn_cvt_pkrtz(xv.x, xv.y);
            *reinterpret_cast<fp16x2*>(&sX[ob][xr][xc * 2]) = hp;
        }
        __syncthreads();   // sX/sH[ob] visible before next step
    }

    // final h (f32) -> out[B][H]; each thread owns 2 (row, col=c) elements
#pragma unroll
    for (int j = 0; j < 2; ++j) {
        const int row = lk * 4 + (losd ? 0 : 2) + j;
        out[(long)(b0 + row) * H_DIM + c] = hreg[j];
    }
}

extern "C" void kernel_launch(void* const* d_in, const int* in_sizes, int n_in,
                              void* d_out, int out_size, void* d_ws, size_t ws_size,
                              hipStream_t stream) {
    const int*   inst  = (const int*)  d_in[0];
    const float* embed = (const float*)d_in[1];
    const float* Wih   = (const float*)d_in[2];
    const float* Whh   = (const float*)d_in[3];
    const float* bih   = (const float*)d_in[4];
    const float* bhh   = (const float*)d_in[5];
    float* out = (float*)d_out;

    lstm_fused<<<B_TOT / BB, NTHREADS, 0, stream>>>(inst, embed, Wih, Whh, bih, bhh, out);
}